// Round 23
// baseline (1124.624 us; speedup 1.0000x reference)
//
#include <hip/hip_runtime.h>
#include <stdint.h>
#include <math.h>

// RNN predictor: B=2048, T=1024 teacher + FUT=64 AR, H=128.
// Round-23: barrier-free single-wave recurrence, weights AGPR-pinned.
//  - One wave = one block = 4 samples (A-rows {0,4,8,12}): every lane's
//    C reg 0 is real -> epilogue 8 tanh/lane on ALL 64 lanes; the lane's 8
//    h'-values are 16 contiguous pi-layout bytes -> ONE ds_write_b128
//    writes the whole h'. A-read: 4 masked ds_read_b128 (lanes l15%4==0).
//  - NO barriers, SINGLE h buffer: in-wave program order + in-order DS pipe
//    orders write->read (R1/R22-proven mechanism).
//  - 32 S-MFMA via inline asm with "a"-constrained weights: 128 weight regs
//    homed in AGPRs, consumed IN PLACE (R8/R9-proven hazard discipline:
//    s_nop 2 at head, tied s_nop fence before acc reads). This kills R22's
//    ~500 cyc/step v_accvgpr copy tax (VGPR=188 < needed ~230 -> parking).
//  - o via 4 builtin piggyback-MFMAs (Wo col 0, VGPR-resident); lanes
//    l15==0 hold o(sample g); AR feedback = one shfl. o ring + 64-step
//    flush as before.
//  - grid 512 x 64 thr -> 2 independent chains/CU, wall = chain step
//    latency, no phase locking.

#define TLEN  1024
#define FUT   64
#define HID   128
#define SPB   4
#define NT    64
#define NSTEP (TLEN + FUT)

typedef float f32x4 __attribute__((ext_vector_type(4)));
typedef _Float16 f16x8 __attribute__((ext_vector_type(8)));
typedef uint32_t u32x4 __attribute__((ext_vector_type(4)));

__device__ __forceinline__ f16x8 asf16(u32x4 v) {
    return __builtin_bit_cast(f16x8, v);
}
__device__ __forceinline__ float fast_tanh(float v) {
    return 1.0f - 2.0f / (__expf(2.0f * v) + 1.0f);   // saturates correctly
}
__device__ __forceinline__ uint32_t packh(float a, float b) {
    return (uint32_t)__builtin_bit_cast(unsigned short, (_Float16)a)
         | ((uint32_t)__builtin_bit_cast(unsigned short, (_Float16)b) << 16);
}

// 16 MFMA: 4 independent depth-4 chains (accs q=0..3), A in VGPR, W in AGPR
// consumed in place. s_nop 2 head covers VALU-init -> MFMA SrcC hazard.
#define MFMA_QBLOCK(a0, a1, a2, a3, W0_, W1_, W2_, W3_)                      \
    asm volatile(                                                            \
        "s_nop 2\n\t"                                                        \
        "v_mfma_f32_16x16x32_f16 %0, %4, %8, %0\n\t"                         \
        "v_mfma_f32_16x16x32_f16 %1, %4, %12, %1\n\t"                        \
        "v_mfma_f32_16x16x32_f16 %2, %4, %16, %2\n\t"                        \
        "v_mfma_f32_16x16x32_f16 %3, %4, %20, %3\n\t"                        \
        "v_mfma_f32_16x16x32_f16 %0, %5, %9, %0\n\t"                         \
        "v_mfma_f32_16x16x32_f16 %1, %5, %13, %1\n\t"                        \
        "v_mfma_f32_16x16x32_f16 %2, %5, %17, %2\n\t"                        \
        "v_mfma_f32_16x16x32_f16 %3, %5, %21, %3\n\t"                        \
        "v_mfma_f32_16x16x32_f16 %0, %6, %10, %0\n\t"                        \
        "v_mfma_f32_16x16x32_f16 %1, %6, %14, %1\n\t"                        \
        "v_mfma_f32_16x16x32_f16 %2, %6, %18, %2\n\t"                        \
        "v_mfma_f32_16x16x32_f16 %3, %6, %22, %3\n\t"                        \
        "v_mfma_f32_16x16x32_f16 %0, %7, %11, %0\n\t"                        \
        "v_mfma_f32_16x16x32_f16 %1, %7, %15, %1\n\t"                        \
        "v_mfma_f32_16x16x32_f16 %2, %7, %19, %2\n\t"                        \
        "v_mfma_f32_16x16x32_f16 %3, %7, %23, %3"                            \
        : "+v"(a0), "+v"(a1), "+v"(a2), "+v"(a3)                             \
        : "v"(A0), "v"(A1), "v"(A2), "v"(A3),                                \
          "a"((W0_)[0]), "a"((W0_)[1]), "a"((W0_)[2]), "a"((W0_)[3]),        \
          "a"((W1_)[0]), "a"((W1_)[1]), "a"((W1_)[2]), "a"((W1_)[3]),        \
          "a"((W2_)[0]), "a"((W2_)[1]), "a"((W2_)[2]), "a"((W2_)[3]),        \
          "a"((W3_)[0]), "a"((W3_)[1]), "a"((W3_)[2]), "a"((W3_)[3]))

__global__ __launch_bounds__(NT, 1) void rnn_kernel(
    const float* __restrict__ x,      // [B, T]
    const float* __restrict__ W_ih,   // [H, 1]
    const float* __restrict__ W_hh,   // [H, H]
    const float* __restrict__ b_ih,   // [H]
    const float* __restrict__ b_hh,   // [H]
    const float* __restrict__ W_out,  // [1, H]
    const float* __restrict__ b_out,  // [1]
    float* __restrict__ out)          // [B, T+FUT]
{
    // h: [row s=0..3][pi(k)] fp16, row 256B; pi byte(k)=(k&15)*16+2*(k>>4).
    __shared__ __align__(16) unsigned short hbuf[SPB * HID];   // 1KB, single
    __shared__ __align__(16) float xstg[SPB][128];             // 2KB
    __shared__ __align__(16) float ring[2][SPB][68];           // o ring

    const int lane = threadIdx.x & 63;
    const int l15  = lane & 15;
    const int g    = lane >> 4;
    const int s0   = blockIdx.x * SPB;

    // ---- weights: W_[q][kt] (col j=16q+l15, slot k=16e+4kt+g) -> AGPR ----
    f16x8 W_[8][4], Wo[4];
    float bias[8], wih[8];
    #pragma unroll
    for (int q = 0; q < 8; ++q) {
        const int j = 16 * q + l15;
        const float* r0 = W_hh + (size_t)j * HID;
        #pragma unroll
        for (int kt = 0; kt < 4; ++kt)
            #pragma unroll
            for (int e = 0; e < 8; ++e)
                W_[q][kt][e] = (_Float16)r0[16 * e + 4 * kt + g];
        bias[q] = b_ih[j] + b_hh[j];
        wih[q]  = W_ih[j];
    }
    #pragma unroll
    for (int kt = 0; kt < 4; ++kt)
        #pragma unroll
        for (int e = 0; e < 8; ++e)
            Wo[kt][e] = (l15 == 0) ? (_Float16)W_out[16 * e + 4 * kt + g]
                                   : (_Float16)0.0f;
    const float bo = b_out[0];

    // ---- LDS byte offsets ----
    const int s_ = l15 >> 2;          // A-read row, lanes l15%4==0 active
    int aoff[4];
    #pragma unroll
    for (int kt = 0; kt < 4; ++kt)
        aoff[kt] = s_ * 256 + (4 * kt + g) * 16;
    const int woff = g * 256 + l15 * 16;   // h'-write: ALL lanes, 16B each

    #pragma unroll
    for (int it = 0; it < 4; ++it)         // zero h (256 u32)
        ((uint32_t*)hbuf)[it * NT + lane] = 0;

    u32x4 A0 = {0,0,0,0}, A1 = A0, A2 = A0, A3 = A0;

#define STEP_BODY(IN_EXPR, IS_TEACHER)                                       \
    do {                                                                     \
        /* A-fragments of h (reads precede this step's writes) */            \
        if ((l15 & 3) == 0) {                                                \
            A0 = *(const u32x4*)((const char*)hbuf + aoff[0]);               \
            A1 = *(const u32x4*)((const char*)hbuf + aoff[1]);               \
            A2 = *(const u32x4*)((const char*)hbuf + aoff[2]);               \
            A3 = *(const u32x4*)((const char*)hbuf + aoff[3]);               \
        }                                                                    \
        f32x4 zz = {0.f,0.f,0.f,0.f};                                        \
        f32x4 s0v=zz,s1v=zz,s2v=zz,s3v=zz,s4v=zz,s5v=zz,s6v=zz,s7v=zz;       \
        MFMA_QBLOCK(s0v, s1v, s2v, s3v, W_[0], W_[1], W_[2], W_[3]);         \
        MFMA_QBLOCK(s4v, s5v, s6v, s7v, W_[4], W_[5], W_[6], W_[7]);         \
        f32x4 ovv = zz;                                                      \
        ovv = __builtin_amdgcn_mfma_f32_16x16x32_f16(asf16(A0), Wo[0], ovv, 0, 0, 0); \
        ovv = __builtin_amdgcn_mfma_f32_16x16x32_f16(asf16(A1), Wo[1], ovv, 0, 0, 0); \
        ovv = __builtin_amdgcn_mfma_f32_16x16x32_f16(asf16(A2), Wo[2], ovv, 0, 0, 0); \
        ovv = __builtin_amdgcn_mfma_f32_16x16x32_f16(asf16(A3), Wo[3], ovv, 0, 0, 0); \
        asm volatile("s_nop 7\n\ts_nop 7"                                    \
            : "+v"(s0v), "+v"(s1v), "+v"(s2v), "+v"(s3v),                    \
              "+v"(s4v), "+v"(s5v), "+v"(s6v), "+v"(s7v));                   \
        const float oval = ovv[0] + bo;   /* o_{i-1}[g] at lanes l15==0 */   \
        if ((IS_TEACHER) ? (i > 0 && l15 == 0) : (l15 == 0))                 \
            ring[((i - 1) >> 6) & 1][g][(i - 1) & 63] = oval;                \
        const float in = (IN_EXPR);                                          \
        const float h0 = fast_tanh(s0v[0] + bias[0] + in * wih[0]);          \
        const float h1 = fast_tanh(s1v[0] + bias[1] + in * wih[1]);          \
        const float h2 = fast_tanh(s2v[0] + bias[2] + in * wih[2]);          \
        const float h3 = fast_tanh(s3v[0] + bias[3] + in * wih[3]);          \
        const float h4 = fast_tanh(s4v[0] + bias[4] + in * wih[4]);          \
        const float h5 = fast_tanh(s5v[0] + bias[5] + in * wih[5]);          \
        const float h6 = fast_tanh(s6v[0] + bias[6] + in * wih[6]);          \
        const float h7 = fast_tanh(s7v[0] + bias[7] + in * wih[7]);          \
        u32x4 pk;                                                            \
        pk[0] = packh(h0, h1);                                               \
        pk[1] = packh(h2, h3);                                               \
        pk[2] = packh(h4, h5);                                               \
        pk[3] = packh(h6, h7);                                               \
        *(u32x4*)((char*)hbuf + woff) = pk;                                  \
    } while (0)

    // ================= teacher-forced loop =================
    for (int i = 0; i < TLEN; ++i) {
        if ((i & 127) == 0) {         // refill x: 4 samples x 128 t
            const int s = lane >> 4, t0 = (lane & 15) * 8;
            const float* xp = &x[(size_t)(s0 + s) * TLEN + i + t0];
            *(f32x4*)&xstg[s][t0]     = *(const f32x4*)(xp);
            *(f32x4*)&xstg[s][t0 + 4] = *(const f32x4*)(xp + 4);
        }
        if (i > 64 && (i & 63) == 1) {   // flush o ring (64 lanes = 64 f32x4)
            const int q = ((i - 65) >> 6) & 1;
            const int s = lane >> 4, c4 = (lane & 15) * 4;
            const f32x4 v = *(const f32x4*)&ring[q][s][c4];
            *(f32x4*)&out[(size_t)(s0 + s) * NSTEP + (i - 65) + c4] = v;
        }
        STEP_BODY(xstg[g][i & 127], 1);
    }

    // ================= autoregressive loop =================
    for (int i = TLEN; i < NSTEP; ++i) {
        if ((i & 63) == 1) {             // flush (fires at i=1025)
            const int q = ((i - 65) >> 6) & 1;
            const int s = lane >> 4, c4 = (lane & 15) * 4;
            const f32x4 v = *(const f32x4*)&ring[q][s][c4];
            *(f32x4*)&out[(size_t)(s0 + s) * NSTEP + (i - 65) + c4] = v;
        }
        STEP_BODY(__shfl(oval, g << 4), 0);
    }
#undef STEP_BODY

    // tail: o_{NSTEP-1} = wout . h_{NSTEP}
    {
        if ((l15 & 3) == 0) {
            A0 = *(const u32x4*)((const char*)hbuf + aoff[0]);
            A1 = *(const u32x4*)((const char*)hbuf + aoff[1]);
            A2 = *(const u32x4*)((const char*)hbuf + aoff[2]);
            A3 = *(const u32x4*)((const char*)hbuf + aoff[3]);
        }
        f32x4 ovv = {0.f, 0.f, 0.f, 0.f};
        ovv = __builtin_amdgcn_mfma_f32_16x16x32_f16(asf16(A0), Wo[0], ovv, 0, 0, 0);
        ovv = __builtin_amdgcn_mfma_f32_16x16x32_f16(asf16(A1), Wo[1], ovv, 0, 0, 0);
        ovv = __builtin_amdgcn_mfma_f32_16x16x32_f16(asf16(A2), Wo[2], ovv, 0, 0, 0);
        ovv = __builtin_amdgcn_mfma_f32_16x16x32_f16(asf16(A3), Wo[3], ovv, 0, 0, 0);
        if (l15 == 0)
            ring[0][g][63] = ovv[0] + bo;   // (1087>>6)&1 = 0
    }
    // flush t = 1024..1087 (ring parity 0)
    {
        const int s = lane >> 4, c4 = (lane & 15) * 4;
        const f32x4 v = *(const f32x4*)&ring[0][s][c4];
        *(f32x4*)&out[(size_t)(s0 + s) * NSTEP + TLEN + c4] = v;
    }
}

extern "C" void kernel_launch(void* const* d_in, const int* in_sizes, int n_in,
                              void* d_out, int out_size, void* d_ws, size_t ws_size,
                              hipStream_t stream) {
    const float* x     = (const float*)d_in[0];
    const float* W_ih  = (const float*)d_in[1];
    const float* W_hh  = (const float*)d_in[2];
    const float* b_ih  = (const float*)d_in[3];
    const float* b_hh  = (const float*)d_in[4];
    const float* W_out = (const float*)d_in[5];
    const float* b_out = (const float*)d_in[6];
    float* out = (float*)d_out;

    dim3 grid(2048 / SPB);   // 512 single-wave blocks -> 2 chains/CU
    dim3 block(NT);
    rnn_kernel<<<grid, block, 0, stream>>>(x, W_ih, W_hh, b_ih, b_hh,
                                           W_out, b_out, out);
}